// Round 1
// baseline (109.915 us; speedup 1.0000x reference)
//
#include <hip/hip_runtime.h>

#define NT 256

// ws accumulator layout (floats): [0..3] l2 sums per level, [4..7] cc sums per level
// smem layout carved per level: ring[WIN][5][CW], rawI[RW], rawJ[RW], red[16]
#define SMEM_FLOATS 12096  // max: 9*5*256 + 2*(256+16) + 16 = 12064

template<int W, int H, int WIN, int SCALE, int CW, int RCHUNK>
__device__ void level_block(const float* __restrict__ yh,
                            const float* __restrict__ y,
                            float* smem, int sub, float* ws_acc, int level)
{
    constexpr int HW = WIN / 2;
    constexpr int RW = CW + 2 * HW;

    float* ring = smem;                  // WIN*5*CW
    float* rawI = ring + WIN * 5 * CW;   // RW
    float* rawJ = rawI + RW;             // RW
    float* red  = rawJ + RW;             // 16

    constexpr int STRIPS = W / CW;
    constexpr int CHUNKS = H / RCHUNK;
    int b     = sub / (STRIPS * CHUNKS);
    int rem   = sub % (STRIPS * CHUNKS);
    int chunk = rem / STRIPS;
    int strip = rem % STRIPS;
    int r0 = chunk * RCHUNK, r1 = r0 + RCHUNK;
    int c0 = strip * CW;

    const float* Jimg = yh + (size_t)b * (size_t)W * (size_t)H;
    const float* Yimg = y  + (size_t)b * 512 * 512;

    int t = threadIdx.x;

    float vI = 0.f, vJ = 0.f, vII = 0.f, vJJ = 0.f, vIJ = 0.f;
    float l2acc = 0.f, ccacc = 0.f;

    for (int r = r0 - HW; r < r1 + HW; ++r) {
        if (r >= 0 && r < H) {
            // --- raw row (with column halo) into LDS ---
            for (int i = t; i < RW; i += NT) {
                int j = c0 - HW + i;
                float I = 0.f, J = 0.f;
                if (j >= 0 && j < W) {
                    J = Jimg[(size_t)r * W + j];
                    if (SCALE == 1) {
                        I = Yimg[(size_t)r * 512 + j];
                    } else {
                        constexpr int OFF = (SCALE - 2) / 2;
                        int rr = SCALE * r + OFF;
                        int cc = SCALE * j + OFF;
                        const float* p = Yimg + (size_t)rr * 512 + cc;
                        I = 0.25f * (p[0] + p[1] + p[512] + p[513]);
                    }
                    if (j >= c0 && j < c0 + CW && r >= r0 && r < r1) {
                        float d = J - I;
                        l2acc += d * d;
                    }
                }
                rawI[i] = I;
                rawJ[i] = J;
            }
            __syncthreads();
            // --- horizontal WIN-tap sums for owned column, push to ring, add to vertical sums ---
            if (t < CW) {
                float sI = 0.f, sJ = 0.f, sII = 0.f, sJJ = 0.f, sIJ = 0.f;
#pragma unroll
                for (int k = 0; k < WIN; ++k) {
                    float I = rawI[t + k];
                    float J = rawJ[t + k];
                    sI += I; sJ += J;
                    sII += I * I; sJJ += J * J; sIJ += I * J;
                }
                int slot = r % WIN;
                float* rp = ring + (size_t)slot * 5 * CW;
                rp[0 * CW + t] = sI;
                rp[1 * CW + t] = sJ;
                rp[2 * CW + t] = sII;
                rp[3 * CW + t] = sJJ;
                rp[4 * CW + t] = sIJ;
                vI += sI; vJ += sJ; vII += sII; vJJ += sJJ; vIJ += sIJ;
            }
            __syncthreads();
        }
        int yrow = r - HW;
        if (yrow >= r0 && yrow < r1 && t < CW) {
            // --- emit output row yrow ---
            const float wsq = (float)(WIN * WIN);
            float cross = vIJ - vI * vJ / wsq;
            float Ivar  = vII - vI * vI / wsq;
            float Jvar  = vJJ - vJ * vJ / wsq;
            float cc = cross * cross / (Ivar * Jvar + 1e-8f);
            ccacc += cc;
            // subtract the row leaving the vertical window
            int rl = yrow - HW;
            if (rl >= 0) {
                int slot = rl % WIN;
                float* rp = ring + (size_t)slot * 5 * CW;
                vI  -= rp[0 * CW + t];
                vJ  -= rp[1 * CW + t];
                vII -= rp[2 * CW + t];
                vJJ -= rp[3 * CW + t];
                vIJ -= rp[4 * CW + t];
            }
        }
    }

    // --- block reduction of l2acc, ccacc ---
    __syncthreads();
#pragma unroll
    for (int off = 32; off > 0; off >>= 1) {
        l2acc += __shfl_down(l2acc, off);
        ccacc += __shfl_down(ccacc, off);
    }
    int wave = t >> 6, lane = t & 63;
    if (lane == 0) { red[wave] = l2acc; red[8 + wave] = ccacc; }
    __syncthreads();
    if (t == 0) {
        float l2t = 0.f, cct = 0.f;
#pragma unroll
        for (int w = 0; w < NT / 64; ++w) { l2t += red[w]; cct += red[8 + w]; }
        atomicAdd(&ws_acc[level], l2t);
        atomicAdd(&ws_acc[4 + level], cct);
    }
}

__global__ __launch_bounds__(NT)
void hier_loss_kernel(const float* __restrict__ yh0, const float* __restrict__ yh1,
                      const float* __restrict__ yh2, const float* __restrict__ yh3,
                      const float* __restrict__ y, float* ws_acc)
{
    __shared__ float smem[SMEM_FLOATS];
    int bid = blockIdx.x;
    if (bid < 512) {
        // level 0: 512x512, win 9, 2 col strips x 8 row chunks x 32 imgs
        level_block<512, 512, 9, 1, 256, 64>(yh0, y, smem, bid, ws_acc, 0);
    } else if (bid < 640) {
        // level 1: 256x256, win 9, 1 strip x 4 chunks x 32
        level_block<256, 256, 9, 2, 256, 64>(yh1, y, smem, bid - 512, ws_acc, 1);
    } else if (bid < 704) {
        // level 2: 128x128, win 7, 1 strip x 2 chunks x 32
        level_block<128, 128, 7, 4, 128, 64>(yh2, y, smem, bid - 640, ws_acc, 2);
    } else {
        // level 3: 64x64, win 5, 1 strip x 1 chunk x 32
        level_block<64, 64, 5, 8, 64, 64>(yh3, y, smem, bid - 704, ws_acc, 3);
    }
}

__global__ void hier_finalize_kernel(const float* __restrict__ ws_acc, float* __restrict__ out)
{
    if (blockIdx.x == 0 && threadIdx.x == 0) {
        const float wts[4] = {1.0f, 0.5f, 0.25f, 0.125f};
        float total = 0.f;
#pragma unroll
        for (int l = 0; l < 4; ++l) {
            float l2 = ws_acc[l] / 32.0f;              // mean over batch of spatial sums
            float ncc = -ws_acc[4 + l] / (32.0f * 100.0f);
            float ll = wts[l] * (l2 + ncc) * 0.5f;     // / N_LOSSES
            out[1 + l] = ll;
            total += ll;
        }
        out[0] = total;
    }
}

extern "C" void kernel_launch(void* const* d_in, const int* in_sizes, int n_in,
                              void* d_out, int out_size, void* d_ws, size_t ws_size,
                              hipStream_t stream)
{
    const float* yh0 = (const float*)d_in[0];
    const float* yh1 = (const float*)d_in[1];
    const float* yh2 = (const float*)d_in[2];
    const float* yh3 = (const float*)d_in[3];
    const float* y   = (const float*)d_in[4];
    float* ws_acc = (float*)d_ws;
    float* out = (float*)d_out;

    hipMemsetAsync(ws_acc, 0, 8 * sizeof(float), stream);
    hier_loss_kernel<<<736, NT, 0, stream>>>(yh0, yh1, yh2, yh3, y, ws_acc);
    hier_finalize_kernel<<<1, 64, 0, stream>>>(ws_acc, out);
}